// Round 1
// baseline (817.657 us; speedup 1.0000x reference)
//
#include <hip/hip_runtime.h>

// Net_23484881175023: conv1d(k=3,stride=3) -> LSTM(input=1, hidden=10, T=8192) -> Linear(10,3)
// B=512, L=24576, Lp=8192.
//
// Latency-bound sequential recurrence. One wave per batch element (512 waves,
// spread over all 256 CUs). Lane layout: lane = hid*4 + gate_type (40 active
// lanes), so i,f,g,o of hidden unit h live in quad {4h..4h+3}.
//
// Chain-shortening tricks vs previous version:
//  - smul (= -log2e, or -2*log2e for the g gate) folded into w_ih/w_hh/bias at
//    init, so the gate pre-activation feeds exp2 directly (no dependent mul).
//  - cell state tracked pre-scaled: cs = -2*log2e * c. The cell exp2 reads cs
//    directly; the -2log2e scale of the update term is folded into off-path
//    constants C4 = -4*log2e, C2 = +2*log2e:
//       cs = f*cs + fma(i*g_sig, C4, i*C2)
//  - h = fma(s2, 2*o, -o): 2*o precomputed off-path after the o-gather, -o via
//    fma negate modifier -> single dependent op after the cell rcp.
//  - dot(h, w_hh) as 4 chains (3,3,2,2) + 2-level add tree: depth 5 vs 6.

#define DEV __device__ __forceinline__

DEV float rl_f(float v, int lane) {
  return __int_as_float(__builtin_amdgcn_readlane(__float_as_int(v), lane));
}

template <int CTRL>
DEV float quad_bcast(float v) {
#if __has_builtin(__builtin_amdgcn_mov_dpp)
  return __int_as_float(__builtin_amdgcn_mov_dpp(__float_as_int(v), CTRL, 0xF, 0xF, true));
#else
  return __int_as_float(__builtin_amdgcn_update_dpp(0, __float_as_int(v), CTRL, 0xF, 0xF, true));
#endif
}

DEV float fast_exp2(float x) {
#if __has_builtin(__builtin_amdgcn_exp2f)
  return __builtin_amdgcn_exp2f(x);
#else
  return __exp2f(x);
#endif
}

DEV float fast_rcp(float x) { return __builtin_amdgcn_rcpf(x); }

constexpr int kB = 512;
constexpr int kL = 24576;
constexpr int kLp = 8192;      // kL / 3
constexpr int kHid = 10;
constexpr int kChunk = 64;     // timesteps per chunk (one ct per lane)
constexpr int kNChunk = kLp / kChunk;  // 128

__global__ __launch_bounds__(64, 1) void lstm_fused(
    const float* __restrict__ x,       // (B, L, 1)
    const float* __restrict__ conv_w,  // (1,1,3)
    const float* __restrict__ conv_b,  // (1,)
    const float* __restrict__ w_ih,    // (40,1)
    const float* __restrict__ w_hh,    // (40,10)
    const float* __restrict__ b_ih,    // (40,)
    const float* __restrict__ b_hh,    // (40,)
    const float* __restrict__ mlp_w,   // (3,10)
    const float* __restrict__ mlp_b,   // (3,)
    float* __restrict__ out) {         // (B,3)
  const int lane = threadIdx.x & 63;
  const int b = blockIdx.x;

  const int hid = lane >> 2;   // 0..9 for active lanes
  const int gt = lane & 3;     // 0:i 1:f 2:g 3:o (torch gate order)
  const bool active = (lane < 40);
  const int r = active ? (gt * kHid + hid) : 0;  // row in the 4H-stacked weights

  // uniform conv params (scalar loads)
  const float cw0 = conv_w[0], cw1 = conv_w[1], cw2 = conv_w[2];
  const float cbv = conv_b[0];

  constexpr float kL2E = 1.4426950408889634f;  // log2(e)
  // gate g uses sigmoid(2x) (tanh folding); i/f/o use sigmoid(x).
  // Fold the exp2 argument scale into the weights so the dot product directly
  // produces the exp2 input.
  const float smul = (gt == 2) ? (-2.0f * kL2E) : (-kL2E);

  const float wih = w_ih[r] * smul;
  const float bsum = (b_ih[r] + b_hh[r]) * smul;
  const float* wr = w_hh + r * kHid;
  const float w0 = wr[0] * smul, w1 = wr[1] * smul, w2 = wr[2] * smul;
  const float w3 = wr[3] * smul, w4 = wr[4] * smul, w5 = wr[5] * smul;
  const float w6 = wr[6] * smul, w7 = wr[7] * smul, w8 = wr[8] * smul;
  const float w9 = wr[9] * smul;

  // cell-update constants (cs = -2*log2e * c is the tracked state):
  //   cs_new = f*cs + (-2L2E)*(2*i*g - i) = f*cs + (C4*i*g + C2*i)
  const float C4 = -4.0f * kL2E;
  const float C2 = 2.0f * kL2E;

  const float* xb = x + (size_t)b * kL;
  const int xoff = lane * 3;

  // prefetch chunk 0's x values
  float x0 = xb[xoff + 0];
  float x1 = xb[xoff + 1];
  float x2 = xb[xoff + 2];

  float h = 0.0f;   // lane's quad value of h[hid]
  float cs = 0.0f;  // -2*log2e * c[hid]

  for (int ch = 0; ch < kNChunk; ++ch) {
    // conv output for timestep (ch*64 + lane), all 64 lanes
    float ct = fmaf(x2, cw2, fmaf(x1, cw1, fmaf(x0, cw0, cbv)));
    ct = fmaxf(ct, 0.0f);

    // prefetch next chunk (consumed after the 64-step inner loop)
    if (ch + 1 < kNChunk) {
      const float* xn = xb + (size_t)(ch + 1) * (kChunk * 3) + xoff;
      x0 = xn[0];
      x1 = xn[1];
      x2 = xn[2];
    }

#pragma unroll 8
    for (int t = 0; t < kChunk; ++t) {
      // input-side preactivation, pre-scaled by smul (off critical path)
      const float ctv = rl_f(ct, t);
      const float xg = fmaf(ctv, wih, bsum);

      // dot(h, w_hh[r]) * smul via readlane broadcasts, 4 chains + add tree
      const float h0 = rl_f(h, 0), h1 = rl_f(h, 4), h2 = rl_f(h, 8);
      const float h3 = rl_f(h, 12), h4 = rl_f(h, 16), h5 = rl_f(h, 20);
      const float h6 = rl_f(h, 24), h7 = rl_f(h, 28), h8 = rl_f(h, 32);
      const float h9 = rl_f(h, 36);
      float pA = fmaf(h0, w0, xg);
      pA = fmaf(h1, w1, pA);
      pA = fmaf(h2, w2, pA);
      float pB = h3 * w3;
      pB = fmaf(h4, w4, pB);
      pB = fmaf(h5, w5, pB);
      float pC = h6 * w6;
      pC = fmaf(h7, w7, pC);
      float pD = h8 * w8;
      pD = fmaf(h9, w9, pD);
      const float pre = (pA + pB) + (pC + pD);  // already scaled for exp2

      // unified activation: a = sigmoid(pre) for i/f/o, sigmoid(2*pre) for g
      const float a = fast_rcp(1.0f + fast_exp2(pre));

      // gather the quad's i,f,g,o (every lane, redundant across the quad)
      const float iv = quad_bcast<0x00>(a);
      const float fv = quad_bcast<0x55>(a);
      const float gv = quad_bcast<0xAA>(a);  // sigma(2g); tanh(g) = 2*gv - 1
      const float ov = quad_bcast<0xFF>(a);
      const float ov2 = ov + ov;  // off-path

      // cs = f*cs + (C4*i*g + C2*i)   (pre-scaled cell state)
      const float pig = iv * gv;
      const float ti = iv * C2;  // off-path w.r.t. pig
      const float u2 = fmaf(pig, C4, ti);
      cs = fmaf(fv, cs, u2);

      // h = o * tanh(c) = 2*o*sigma(2c) - o = fma(s2, 2o, -o)
      const float s2 = fast_rcp(1.0f + fast_exp2(cs));
      h = fmaf(s2, ov2, -ov);
    }
  }

  // epilogue: out[b][m] = sum_k h[k]*mlp_w[m][k] + mlp_b[m], m = 0..2
  if (lane < 3) {
    const float* mw = mlp_w + lane * kHid;
    float acc = mlp_b[lane];
    acc = fmaf(rl_f(h, 0), mw[0], acc);
    acc = fmaf(rl_f(h, 4), mw[1], acc);
    acc = fmaf(rl_f(h, 8), mw[2], acc);
    acc = fmaf(rl_f(h, 12), mw[3], acc);
    acc = fmaf(rl_f(h, 16), mw[4], acc);
    acc = fmaf(rl_f(h, 20), mw[5], acc);
    acc = fmaf(rl_f(h, 24), mw[6], acc);
    acc = fmaf(rl_f(h, 28), mw[7], acc);
    acc = fmaf(rl_f(h, 32), mw[8], acc);
    acc = fmaf(rl_f(h, 36), mw[9], acc);
    out[b * 3 + lane] = acc;
  }
}

extern "C" void kernel_launch(void* const* d_in, const int* in_sizes, int n_in,
                              void* d_out, int out_size, void* d_ws, size_t ws_size,
                              hipStream_t stream) {
  const float* x = (const float*)d_in[0];
  const float* conv_w = (const float*)d_in[1];
  const float* conv_b = (const float*)d_in[2];
  const float* w_ih = (const float*)d_in[3];
  const float* w_hh = (const float*)d_in[4];
  const float* b_ih = (const float*)d_in[5];
  const float* b_hh = (const float*)d_in[6];
  const float* mlp_w = (const float*)d_in[7];
  const float* mlp_b = (const float*)d_in[8];
  float* out = (float*)d_out;

  // 512 blocks x 64 threads = 512 waves; one wave per batch element,
  // spread across all 256 CUs (2 waves/CU).
  dim3 grid(kB), block(64);
  hipLaunchKernelGGL(lstm_fused, grid, block, 0, stream, x, conv_w, conv_b,
                     w_ih, w_hh, b_ih, b_hh, mlp_w, mlp_b, out);
}

// Round 3
// 780.051 us; speedup vs baseline: 1.0482x; 1.0482x over previous
//
#include <hip/hip_runtime.h>

// Net_23484881175023: conv1d(k=3,stride=3) -> LSTM(input=1, hidden=10, T=8192) -> Linear(10,3)
// B=512, L=24576, Lp=8192.
//
// Latency/issue-bound sequential recurrence; one wave per batch element.
// Lane layout: lane = hid*4 + gate (40 active lanes); i,f,g,o of hidden unit
// h live in quad {4h..4h+3}; h and c are quad-uniform after each step.
//
// Round-2 change: the h-dot (the biggest instruction block, 23 ops) is
// compressed with packed-f16 dot products:
//   - one DPP row_shl:4 (lane i <- lane i+4) + one v_cvt_pkrtz packs the pair
//     (h_{2j}, h_{2j+1}) into even-hid quads (2 instrs for ALL pairs)
//   - 4 packed readlanes + 4 v_dot2_f32_f16 replace 8 readlanes + 8 FMAs
//   - f32 FMA head for h0,h1 keeps the dependence depth at 6 (unchanged)
// Dot block 23 -> 16 instrs; step total ~41 -> ~34.
//
// NOTE: cvt_pkrtz returns __fp16x2 while fdot2 wants _Float16x2 on this
// toolchain -> bit_cast shim (same 32-bit layout).

#define DEV __device__ __forceinline__

typedef _Float16 half2v __attribute__((ext_vector_type(2)));

DEV float rl_f(float v, int lane) {
  return __int_as_float(__builtin_amdgcn_readlane(__float_as_int(v), lane));
}

DEV half2v rl_h2(half2v v, int lane) {
  int i = __builtin_amdgcn_readlane(__builtin_bit_cast(int, v), lane);
  return __builtin_bit_cast(half2v, i);
}

DEV half2v pkrtz(float a, float b) {
  return __builtin_bit_cast(half2v, __builtin_amdgcn_cvt_pkrtz(a, b));
}

template <int CTRL>
DEV float dpp_f(float v) {
#if __has_builtin(__builtin_amdgcn_mov_dpp)
  return __int_as_float(__builtin_amdgcn_mov_dpp(__float_as_int(v), CTRL, 0xF, 0xF, true));
#else
  return __int_as_float(__builtin_amdgcn_update_dpp(0, __float_as_int(v), CTRL, 0xF, 0xF, true));
#endif
}

DEV float fast_exp2(float x) {
#if __has_builtin(__builtin_amdgcn_exp2f)
  return __builtin_amdgcn_exp2f(x);
#else
  return __exp2f(x);
#endif
}

DEV float fast_rcp(float x) { return __builtin_amdgcn_rcpf(x); }

#if __has_builtin(__builtin_amdgcn_fdot2)
#define USE_FDOT2 1
#else
#define USE_FDOT2 0
#endif

constexpr int kB = 512;
constexpr int kL = 24576;
constexpr int kLp = 8192;      // kL / 3
constexpr int kHid = 10;
constexpr int kChunk = 64;     // timesteps per chunk (one ct per lane)
constexpr int kNChunk = kLp / kChunk;  // 128

__global__ __launch_bounds__(256, 1) void lstm_fused(
    const float* __restrict__ x,       // (B, L, 1)
    const float* __restrict__ conv_w,  // (1,1,3)
    const float* __restrict__ conv_b,  // (1,)
    const float* __restrict__ w_ih,    // (40,1)
    const float* __restrict__ w_hh,    // (40,10)
    const float* __restrict__ b_ih,    // (40,)
    const float* __restrict__ b_hh,    // (40,)
    const float* __restrict__ mlp_w,   // (3,10)
    const float* __restrict__ mlp_b,   // (3,)
    float* __restrict__ out) {         // (B,3)
  const int lane = threadIdx.x & 63;
  const int wave = threadIdx.x >> 6;
  const int b = blockIdx.x * 4 + wave;

  const int hid = lane >> 2;   // 0..9 for active lanes
  const int gt = lane & 3;     // 0:i 1:f 2:g 3:o (torch gate order)
  const bool active = (lane < 40);
  const int r = active ? (gt * kHid + hid) : 0;  // row in the 4H-stacked weights

  // uniform conv params (scalar loads)
  const float cw0 = conv_w[0], cw1 = conv_w[1], cw2 = conv_w[2];
  const float cbv = conv_b[0];

  constexpr float kL2E = 1.4426950408889634f;  // log2(e)
  // gate g uses sigmoid(2x) (tanh folding); i/f/o use sigmoid(x).
  // Fold the exp2 argument scale into the weights so the dot product directly
  // produces the exp2 input.
  const float smul = (gt == 2) ? (-2.0f * kL2E) : (-kL2E);

  const float wih = w_ih[r] * smul;
  const float bsum = (b_ih[r] + b_hh[r]) * smul;
  const float* wr = w_hh + r * kHid;
  const float w0s = wr[0] * smul, w1s = wr[1] * smul;
  const float w2s = wr[2] * smul, w3s = wr[3] * smul, w4s = wr[4] * smul;
  const float w5s = wr[5] * smul, w6s = wr[6] * smul, w7s = wr[7] * smul;
  const float w8s = wr[8] * smul, w9s = wr[9] * smul;

#if USE_FDOT2
  const half2v wp1 = pkrtz(w2s, w3s);
  const half2v wp2 = pkrtz(w4s, w5s);
  const half2v wp3 = pkrtz(w6s, w7s);
  const half2v wp4 = pkrtz(w8s, w9s);
#endif

  // cell-update constants (cs = -2*log2e * c is the tracked state):
  //   cs_new = f*cs + (-2L2E)*(2*i*g - i) = f*cs + (C4*i*g + C2*i)
  const float C4 = -4.0f * kL2E;
  const float C2 = 2.0f * kL2E;

  const float* xb = x + (size_t)b * kL;
  const int xoff = lane * 3;

  // prefetch chunk 0's x values
  float x0 = xb[xoff + 0];
  float x1 = xb[xoff + 1];
  float x2 = xb[xoff + 2];

  float h = 0.0f;   // lane's quad value of h[hid]
  float cs = 0.0f;  // -2*log2e * c[hid]

  for (int ch = 0; ch < kNChunk; ++ch) {
    // conv output for timestep (ch*64 + lane), all 64 lanes
    float ct = fmaf(x2, cw2, fmaf(x1, cw1, fmaf(x0, cw0, cbv)));
    ct = fmaxf(ct, 0.0f);

    // prefetch next chunk (consumed after the 64-step inner loop)
    if (ch + 1 < kNChunk) {
      const float* xn = xb + (size_t)(ch + 1) * (kChunk * 3) + xoff;
      x0 = xn[0];
      x1 = xn[1];
      x2 = xn[2];
    }

#pragma unroll 8
    for (int t = 0; t < kChunk; ++t) {
      // input-side preactivation, pre-scaled by smul (off critical path)
      const float ctv = rl_f(ct, t);
      const float xg = fmaf(ctv, wih, bsum);

      float pre;
#if USE_FDOT2
      // f32 head for h0,h1 (keeps chain depth at 6), packed f16 for h2..h9.
      const float h0 = rl_f(h, 0), h1 = rl_f(h, 4);
      // pack (h_{2j}, h_{2j+1}) in even-hid quads: lane i <- lane i+4
      const float hnb = dpp_f<0x104>(h);  // row_shl:4 == shfl_down 4
      const half2v hpk = pkrtz(h, hnb);
      const half2v p23 = rl_h2(hpk, 8);
      const half2v p45 = rl_h2(hpk, 16);
      const half2v p67 = rl_h2(hpk, 24);
      const half2v p89 = rl_h2(hpk, 32);
      float pA = fmaf(h0, w0s, xg);
      pA = fmaf(h1, w1s, pA);
      pA = __builtin_amdgcn_fdot2(p23, wp1, pA, false);
      float pB = __builtin_amdgcn_fdot2(p45, wp2, 0.0f, false);
      pB = __builtin_amdgcn_fdot2(p67, wp3, pB, false);
      const float pC = __builtin_amdgcn_fdot2(p89, wp4, 0.0f, false);
      pre = (pA + pC) + pB;
#else
      const float h0 = rl_f(h, 0), h1 = rl_f(h, 4), h2 = rl_f(h, 8);
      const float h3 = rl_f(h, 12), h4 = rl_f(h, 16), h5 = rl_f(h, 20);
      const float h6 = rl_f(h, 24), h7 = rl_f(h, 28), h8 = rl_f(h, 32);
      const float h9 = rl_f(h, 36);
      float pA = fmaf(h0, w0s, xg);
      pA = fmaf(h1, w1s, pA);
      pA = fmaf(h2, w2s, pA);
      float pB = h3 * w3s;
      pB = fmaf(h4, w4s, pB);
      pB = fmaf(h5, w5s, pB);
      float pC = h6 * w6s;
      pC = fmaf(h7, w7s, pC);
      float pD = h8 * w8s;
      pD = fmaf(h9, w9s, pD);
      pre = (pA + pB) + (pC + pD);
#endif

      // unified activation: a = sigmoid(pre) for i/f/o, sigmoid(2*pre) for g
      const float a = fast_rcp(1.0f + fast_exp2(pre));

      // gather the quad's i,f,g,o (every lane, redundant across the quad)
      const float iv = dpp_f<0x00>(a);
      const float fv = dpp_f<0x55>(a);
      const float gv = dpp_f<0xAA>(a);  // sigma(2g); tanh(g) = 2*gv - 1
      const float ov = dpp_f<0xFF>(a);
      const float ov2 = ov + ov;  // off-path

      // cs = f*cs + C2*i + C4*i*g   (pre-scaled cell state)
      const float ti = iv * C2;
      const float pig = iv * gv;
      const float csp = fmaf(fv, cs, ti);     // parallel with pig
      cs = fmaf(pig, C4, csp);

      // h = o * tanh(c) = 2*o*sigma(2c) - o = fma(s2, 2o, -o)
      const float s2 = fast_rcp(1.0f + fast_exp2(cs));
      h = fmaf(s2, ov2, -ov);
    }
  }

  // epilogue: out[b][m] = sum_k h[k]*mlp_w[m][k] + mlp_b[m], m = 0..2
  if (lane < 3) {
    const float* mw = mlp_w + lane * kHid;
    float acc = mlp_b[lane];
    acc = fmaf(rl_f(h, 0), mw[0], acc);
    acc = fmaf(rl_f(h, 4), mw[1], acc);
    acc = fmaf(rl_f(h, 8), mw[2], acc);
    acc = fmaf(rl_f(h, 12), mw[3], acc);
    acc = fmaf(rl_f(h, 16), mw[4], acc);
    acc = fmaf(rl_f(h, 20), mw[5], acc);
    acc = fmaf(rl_f(h, 24), mw[6], acc);
    acc = fmaf(rl_f(h, 28), mw[7], acc);
    acc = fmaf(rl_f(h, 32), mw[8], acc);
    acc = fmaf(rl_f(h, 36), mw[9], acc);
    out[b * 3 + lane] = acc;
  }
}

extern "C" void kernel_launch(void* const* d_in, const int* in_sizes, int n_in,
                              void* d_out, int out_size, void* d_ws, size_t ws_size,
                              hipStream_t stream) {
  const float* x = (const float*)d_in[0];
  const float* conv_w = (const float*)d_in[1];
  const float* conv_b = (const float*)d_in[2];
  const float* w_ih = (const float*)d_in[3];
  const float* w_hh = (const float*)d_in[4];
  const float* b_ih = (const float*)d_in[5];
  const float* b_hh = (const float*)d_in[6];
  const float* mlp_w = (const float*)d_in[7];
  const float* mlp_b = (const float*)d_in[8];
  float* out = (float*)d_out;

  // 128 blocks x 256 threads = 512 waves; one wave per batch element.
  // 4 waves/block land on the 4 SIMDs of a CU -> ~1 wave/SIMD chip-wide.
  dim3 grid(kB / 4), block(256);
  hipLaunchKernelGGL(lstm_fused, grid, block, 0, stream, x, conv_w, conv_b,
                     w_ih, w_hh, b_ih, b_hh, mlp_w, mlp_b, out);
}